// Round 5
// baseline (21788.518 us; speedup 1.0000x reference)
//
#include <hip/hip_runtime.h>

// =====================================================================
// SPINN-style stack LSTM, MI355X.
// 8 groups (one per XCD via HW_REG_XCC_ID) x 16 batch; 32 blocks/group
// (25 "E" reduce-slice blocks x 12 dims, 7 "T" tracker blocks x 9-10
// units). R5: fp32 weights resident in VGPRs for all 511 steps (R4 idea),
// but with BATCH-CHUNKED accumulators (acc[4][4], chunk loop, unroll 1)
// so peak live regs fit the 256 arch-VGPR file -> no scratch spills
// (R4 spilled: 220 VGPR + scratch reloads = 10GB FETCH, 18.7ms).
// E thread: 4 dots x 40k weights (160 regs). T thread: 4 dots x 48k
// (192 regs). Barrier: relaxed agent-scope atomic polls + one
// post-barrier buffer_inv. 1 block/CU forced via 155KB LDS.
// =====================================================================

#define NSTEP 511
#define HB 128
#define SQ 256
#define HD 300
#define DW 600
#define TK 64

#define NB 16
#define NE 25           // E blocks per group
#define JPB 12          // j dims per E block
#define DOTS_E 60       // 5 gates * 12 j
#define KE 640          // padded 600
#define KLE 40          // k per kq-slice (E), 16 slices
#define UPB 10
#define DOTS_T 40       // 4 gates * 10 units
#define KT 1008         // padded 964 (900 fused + 64 hh)
#define KLT 48
#define ASTR 20         // act row stride (floats), 16 slots + pad
#define OUTW 1322

// ---- workspace layout (floats) ----
#define N_WEB 960000            // 25*60*640  E weight slices fp32
#define N_WTB 282240            // 7*40*1008  T fused weight slices fp32
#define N_WTR 97500             // 25*60*65   W_track slices
#define N_TH  16384             // 2*128*64   th double buffer
#define N_STACK 19660800        // 128*256*600
#define N_BAR 1024
#define N_TPK 4096
#define N_WCT 230400            // WcatT (prep only, overlaps stack)

#define OFF_WEB 0
#define OFF_WTB 960000
#define OFF_WTR 1242240
#define OFF_TH  1339744
#define OFF_STACK 1356128
#define OFF_BAR 21016928
#define OFF_TPK 21017952
#define WS_FLOATS 21022048
#define OFF_WCT OFF_STACK

// ---- LDS layout (floats) ----
#define L_ACT 0                 // 1028 skewed rows * ASTR = 20560
#define L_DUMP 20560            // E: 8*EDP=7712, T: 21*TDP=13524
#define EDP 964                 // E dump kq pitch (60*16 + 4 skew)
#define TDP 644                 // T dump kq pitch (40*16 + 4 skew)
#define L_WTR 34084             // 60*65 = 3900
#define L_THL 37984             // 16*65 = 1040
#define L_BRED 39024            // 60(+4)
#define L_TRW 39088             // 511 ints (+1)
#define L_INT 39600             // 96 ints
#define LDS_FLOATS 39696        // 158784 B  (>80KB => 1 block/CU)

__device__ __forceinline__ float sigf(float x) { return 1.0f / (1.0f + __expf(-x)); }

// ---------------------------------------------------------------------
// prep_a: WcatT[256][900], zero th/barrier, pack transitions.
// ---------------------------------------------------------------------
__global__ void prep_a(const float* __restrict__ Wbuf, const float* __restrict__ Ws1,
                       const float* __restrict__ Ws2, const int* __restrict__ trans,
                       float* __restrict__ ws) {
  int idx = blockIdx.x * 256 + threadIdx.x;
  if (idx < N_WCT) {
    int k = idx % 900;
    int m = idx / 900;
    float v = (k < 300) ? Wbuf[k*256 + m]
            : (k < 600) ? Ws1[(k-300)*256 + m]
                        : Ws2[(k-600)*256 + m];
    ws[OFF_WCT + idx] = v;
    return;
  }
  idx -= N_WCT;
  if (idx < N_TH) { ws[OFF_TH + idx] = 0.0f; return; }
  idx -= N_TH;
  if (idx < N_BAR) { ws[OFF_BAR + idx] = 0.0f; return; }
  idx -= N_BAR;
  if (idx < 8*NSTEP) {
    int g = idx / NSTEP, t = idx % NSTEP;
    int w = 0;
    #pragma unroll
    for (int b = 0; b < 16; ++b)
      w |= (trans[(size_t)(g*16 + b)*NSTEP + t] & 1) << b;
    ((int*)(ws + OFF_TPK))[g*NSTEP + t] = w;
  }
}

// ---------------------------------------------------------------------
// prep_b: fp32 transposed weight slices; tracker input projection fused
// with W_ih: WT[col][k<900] = sum_m Wcat[k][m] * W_ih[col][m]  (exact).
// ---------------------------------------------------------------------
__global__ void prep_b(const float* __restrict__ Wih, const float* __restrict__ Whh,
                       const float* __restrict__ Wl, const float* __restrict__ Wr,
                       const float* __restrict__ Wtrk, float* __restrict__ ws) {
  int idx = blockIdx.x * 256 + threadIdx.x;
  if (idx < N_WEB) {
    int k = idx % KE; int rest = idx / KE;
    int dot = rest % DOTS_E; int e = rest / DOTS_E;
    int g = dot / JPB, jj = dot % JPB;
    int col = g*HD + e*JPB + jj;
    float v = 0.0f;
    if (k < 300)      v = Wl[k*1500 + col];          // s2h @ W_left
    else if (k < 600) v = Wr[(k-300)*1500 + col];    // s1h @ W_right
    ws[OFF_WEB + idx] = v;
    return;
  }
  idx -= N_WEB;
  if (idx < N_WTB) {
    int k = idx % KT; int rest = idx / KT;
    int dot = rest % DOTS_T; int tb = rest / DOTS_T;
    int g = dot / UPB, uu = dot % UPB;
    int ucnt = (tb == 6) ? 10 : 9;
    float v = 0.0f;
    if (uu < ucnt) {
      int col = g*TK + tb*9 + uu;
      if (k < 900) {
        const float* wct = ws + OFF_WCT;
        const float* wi  = Wih + col*256;
        float s = 0.0f;
        #pragma unroll 4
        for (int m = 0; m < 256; ++m) s = fmaf(wct[m*900 + k], wi[m], s);
        v = s;
      } else if (k < 964) {
        v = Whh[col*TK + (k - 900)];
      }
    }
    ws[OFF_WTB + idx] = v;
    return;
  }
  idx -= N_WTB;
  if (idx < N_WTR) {
    int k = idx % 65; int rest = idx / 65;
    int dot = rest % DOTS_E; int e = rest / DOTS_E;
    int g = dot / JPB, jj = dot % JPB;
    ws[OFF_WTR + idx] = (k < 64) ? Wtrk[k*1500 + (g*HD + e*JPB + jj)] : 0.0f;
  }
}

// ---------------------------------------------------------------------
// XCD-local barrier. Data committed to L2 by the vmcnt(0) drain in
// __syncthreads(); polls are relaxed agent atomics (bypass L1); one
// post-barrier buffer_inv refreshes L1 for normal loads.
// ---------------------------------------------------------------------
__device__ __forceinline__ void xbar(int role, unsigned epoch,
                                     unsigned* slots, unsigned* flag,
                                     volatile int* broken) {
  __syncthreads();
  if (role == 0) {
    if (threadIdx.x < 64) {
      int lane = threadIdx.x;
      unsigned spins = 0;
      for (;;) {
        if (*broken) break;
        unsigned v = (lane >= 1 && lane < 32)
            ? __hip_atomic_load(slots + lane, __ATOMIC_RELAXED, __HIP_MEMORY_SCOPE_AGENT)
            : epoch;
        if (__all(v >= epoch)) break;
        __builtin_amdgcn_s_sleep(1);
        if (++spins > 4000000u) { if (lane == 0) *broken = 1; break; }
      }
      if (lane == 0)
        __hip_atomic_store(flag, epoch, __ATOMIC_RELAXED, __HIP_MEMORY_SCOPE_AGENT);
    }
  } else if (threadIdx.x == 0) {
    __hip_atomic_store(slots + role, epoch, __ATOMIC_RELAXED, __HIP_MEMORY_SCOPE_AGENT);
    unsigned spins = 0;
    while (!*broken &&
           __hip_atomic_load(flag, __ATOMIC_RELAXED, __HIP_MEMORY_SCOPE_AGENT) < epoch) {
      __builtin_amdgcn_s_sleep(1);
      if (++spins > 4000000u) *broken = 1;
    }
  }
  __syncthreads();
  asm volatile("buffer_inv" ::: "memory");
}

// ---------------------------------------------------------------------
// E-block P1: thread (q,kq) owns 4 weight cols x 40 k (fp32, VGPRs).
// Batch processed in 4-wide chunks with acc[4][4] (16 regs) so weights +
// acc + temps stay under the 256 arch-VGPR file (R4 lesson: acc[4][16]
// spilled to scratch). Weights re-read per chunk are register reads: free.
// ---------------------------------------------------------------------
__device__ __forceinline__ void e_p1(const float4 (&wf)[4][12],
                                     const float* __restrict__ ab,
                                     float* __restrict__ dmp, int kq, int q,
                                     int nchunk) {
  #pragma unroll 1
  for (int c = 0; c < nchunk; ++c) {
    float acc[4][4];
    #pragma unroll
    for (int d = 0; d < 4; ++d)
      #pragma unroll
      for (int s = 0; s < 4; ++s) acc[d][s] = 0.0f;
    #pragma unroll
    for (int i = 0; i < 10; ++i) {
      #pragma unroll
      for (int kk = 0; kk < 4; ++kk) {
        float4 a = *(const float4*)(ab + (4*i + kk)*ASTR + 4*c);
        #pragma unroll
        for (int d = 0; d < 4; ++d) {
          float w = (kk == 0) ? wf[d][i].x : (kk == 1) ? wf[d][i].y
                  : (kk == 2) ? wf[d][i].z : wf[d][i].w;
          acc[d][0] = fmaf(w, a.x, acc[d][0]);
          acc[d][1] = fmaf(w, a.y, acc[d][1]);
          acc[d][2] = fmaf(w, a.z, acc[d][2]);
          acc[d][3] = fmaf(w, a.w, acc[d][3]);
        }
      }
    }
    // pair-reduce kq <-> kq^8 in-register (stays in-wave)
    #pragma unroll
    for (int d = 0; d < 4; ++d)
      #pragma unroll
      for (int s = 0; s < 4; ++s)
        acc[d][s] += __shfl_xor(acc[d][s], 8, 64);
    if (kq < 8) {
      #pragma unroll
      for (int d = 0; d < 4; ++d)
        *(float4*)(dmp + kq*EDP + (4*q + d)*16 + 4*c) =
            make_float4(acc[d][0], acc[d][1], acc[d][2], acc[d][3]);
    }
  }
}

// ---------------------------------------------------------------------
// main persistent kernel: 256 blocks, 256 threads, 1 block/CU.
// ---------------------------------------------------------------------
__launch_bounds__(256, 1)
__global__ void spinn_kernel(const float* __restrict__ bufs,
                             const float* __restrict__ Wtrans, const float* __restrict__ btrans,
                             const float* __restrict__ bredv,
                             float* __restrict__ ws, float* __restrict__ out) {
  extern __shared__ float lds[];
  int* ibuf = (int*)(lds + L_INT);
  int* redl = ibuf + 16;
  int* shl  = ibuf + 32;
  int* sptr = ibuf + 48;
  int* bptr = ibuf + 64;
  volatile int* broken = ibuf + 82;
  int* role_s = ibuf + 90;
  int* trw = (int*)(lds + L_TRW);

  const int tid = threadIdx.x;

  // ---- runtime XCD-local grouping ----
  unsigned xcc;
  asm volatile("s_getreg_b32 %0, hwreg(HW_REG_XCC_ID)" : "=s"(xcc));
  xcc &= 7u;
  if (tid == 0) {
    unsigned slot = __hip_atomic_fetch_add((unsigned*)(ws + OFF_BAR) + 512 + xcc, 1u,
                                           __ATOMIC_RELAXED, __HIP_MEMORY_SCOPE_AGENT);
    *role_s = (int)slot;
    *broken = 0;
  }
  __syncthreads();
  const int role = *role_s;
  const int group = (int)xcc;
  if (role >= 32) return;

  const int b0 = group * NB;
  const bool isE = (role < NE);
  const int e  = role;
  const int tb = role - NE;
  const int u0 = (tb >= 0) ? tb*9 : 0;
  const int ucnt = (tb == 6) ? 10 : 9;

  unsigned* slots = (unsigned*)(ws + OFF_BAR) + (size_t)group*64;
  unsigned* flag  = slots + 32;

  float* stack = ws + OFF_STACK;
  float* thbuf = ws + OFF_TH;

  float tc_reg = 0.0f;

  // ---- preload this thread's fp32 weight slice into VGPRs (whole run) ----
  // E: wreg[4][0..9] = 160 regs. T: wreg[4][0..11] = 192 regs.
  float4 wreg[4][12];
  if (isE) {
    if (tid < 240) {
      const int q = tid >> 4, kq = tid & 15;
      const float* wb = ws + OFF_WEB;
      #pragma unroll
      for (int d = 0; d < 4; ++d)
        #pragma unroll
        for (int i = 0; i < 10; ++i)
          wreg[d][i] = *(const float4*)(wb + (size_t)(e*DOTS_E + 4*q + d)*KE + kq*KLE + 4*i);
    }
  } else {
    if (tid < 210) {
      const int q = tid / 21, kq = tid % 21;
      const float* wb = ws + OFF_WTB;
      #pragma unroll
      for (int d = 0; d < 4; ++d)
        #pragma unroll
        for (int i = 0; i < 12; ++i)
          wreg[d][i] = *(const float4*)(wb + (size_t)(tb*DOTS_T + 4*q + d)*KT + kq*KLT + 4*i);
    }
  }

  // ---- one-time init ----
  if (tid < 16) { sptr[tid] = 0; bptr[tid] = 0; }
  for (int i = tid; i < NSTEP; i += 256)
    trw[i] = ((const int*)(ws + OFF_TPK))[group*NSTEP + i];
  if (isE) {
    for (int i = tid; i < DOTS_E*65; i += 256)
      lds[L_WTR + i] = ws[OFF_WTR + (size_t)e*DOTS_E*65 + i];
    for (int i = tid; i < DOTS_E; i += 256)
      lds[L_BRED + i] = bredv[(i/JPB)*HD + e*JPB + (i%JPB)];
    for (int i = tid; i < 40*ASTR; i += 256) lds[L_ACT + 615*ASTR + i] = 0.0f; // k 600..639
  } else {
    for (int i = tid; i < 44*ASTR; i += 256) lds[L_ACT + 984*ASTR + i] = 0.0f; // k 964..1007
  }
  __syncthreads();

  unsigned epoch = 0;

  for (int t = 0; t < NSTEP; ++t) {
    // ---- prologue: transition word + compact lists ----
    const int w = trw[t] & 0xFFFF;          // bit=1 -> reduce
    const int nred = __popc(w);
    if (tid < 16) {
      int rank = __popc(w & ((1u << tid) - 1u));
      if ((w >> tid) & 1) redl[rank] = tid; else shl[tid - rank] = tid;
    }
    __syncthreads();

    // ---- P1 staging into LDS (fp32, skewed rows) ----
    if (isE) {
      int r = tid >> 4, lane = tid & 15;
      if (r < nred) {
        int b = redl[r];
        int sp = sptr[b];
        const float* s2p = stack + ((size_t)((b0+b)*SQ + sp-2))*DW;
        const float* s1p = stack + ((size_t)((b0+b)*SQ + sp-1))*DW;
        #pragma unroll
        for (int i = 0; i < 10; ++i) {
          int ch = lane + 16*i;
          if (ch < 150) {
            int sec = ch / 75, kc = ch % 75;
            int dim = kc*4;
            const float* src = (sec == 0) ? s2p : s1p;
            float4 v = *(const float4*)(src + dim);
            int kbase = sec*300 + dim;
            int row0 = (kbase/40)*41 + (kbase%40);
            lds[L_ACT + (row0+0)*ASTR + r] = v.x;
            lds[L_ACT + (row0+1)*ASTR + r] = v.y;
            lds[L_ACT + (row0+2)*ASTR + r] = v.z;
            lds[L_ACT + (row0+3)*ASTR + r] = v.w;
          }
        }
      }
    } else {
      {
        int b = tid >> 4, lane = tid & 15;
        int bp = bptr[b]; if (bp > SQ-1) bp = SQ-1;
        int sp = sptr[b];
        const float* bsrc = bufs + ((size_t)((b0+b)*SQ + bp))*DW;
        const float* s1p = (sp >= 1) ? stack + ((size_t)((b0+b)*SQ + sp-1))*DW : nullptr;
        const float* s2p = (sp >= 2) ? stack + ((size_t)((b0+b)*SQ + sp-2))*DW : nullptr;
        #pragma unroll
        for (int i = 0; i < 15; ++i) {
          int ch = lane + 16*i;
          if (ch < 225) {
            int sec = ch / 75, kc = ch % 75;
            int dim = kc*4;
            const float* src = (sec == 0) ? bsrc : ((sec == 1) ? s1p : s2p);
            float4 v = make_float4(0.f, 0.f, 0.f, 0.f);
            if (src) v = *(const float4*)(src + dim);
            int kbase = sec*300 + dim;
            int row0 = (kbase/48)*49 + (kbase%48);
            lds[L_ACT + (row0+0)*ASTR + b] = v.x;
            lds[L_ACT + (row0+1)*ASTR + b] = v.y;
            lds[L_ACT + (row0+2)*ASTR + b] = v.z;
            lds[L_ACT + (row0+3)*ASTR + b] = v.w;
          }
        }
      }
      { // th(t-1) -> rows 900..963 ; t=0 reads zeroed parity-1 buffer
        int pm = (t - 1) & 1;
        int b = tid >> 4, uc = tid & 15;
        float4 v = *(const float4*)(thbuf + ((size_t)pm*HB + (b0+b))*TK + uc*4);
        float vv[4] = {v.x, v.y, v.z, v.w};
        #pragma unroll
        for (int l = 0; l < 4; ++l) {
          int k = 900 + uc*4 + l;
          int row = (k/48)*49 + (k%48);
          lds[L_ACT + row*ASTR + b] = vv[l];
        }
      }
    }
    __syncthreads();

    // ---- P1 compute (weights from VGPRs, chunked acc) ----
    if (isE) {
      const int nchunk = (nred + 3) >> 2;
      if (nchunk > 0) {
        if (tid < 240) {
          const int q = tid >> 4, kq = tid & 15;
          const float* ab = lds + L_ACT + (kq*41)*ASTR;
          e_p1(wreg, ab, lds + L_DUMP, kq, q, nchunk);
        }
        __syncthreads();
        for (int task = tid; task < DOTS_E*16; task += 256) {
          int dot = task >> 4, s = task & 15;
          float sum = 0.0f;
          #pragma unroll
          for (int kq = 0; kq < 8; ++kq)
            sum += lds[L_DUMP + kq*EDP + dot*16 + s];
          lds[L_DUMP + dot*16 + s] = sum;   // compact a_red (left+right parts)
        }
      }
    } else {
      if (tid < 210) {
        const int q = tid / 21, kq = tid % 21;
        const float* ab = lds + L_ACT + (kq*49)*ASTR;
        float* dmp = lds + L_DUMP + kq*TDP;
        #pragma unroll 1
        for (int c = 0; c < 4; ++c) {
          float acc[4][4];
          #pragma unroll
          for (int d = 0; d < 4; ++d)
            #pragma unroll
            for (int s = 0; s < 4; ++s) acc[d][s] = 0.0f;
          #pragma unroll
          for (int i = 0; i < 12; ++i) {
            #pragma unroll
            for (int kk = 0; kk < 4; ++kk) {
              float4 a = *(const float4*)(ab + (4*i + kk)*ASTR + 4*c);
              #pragma unroll
              for (int d = 0; d < 4; ++d) {
                float wv = (kk == 0) ? wreg[d][i].x : (kk == 1) ? wreg[d][i].y
                         : (kk == 2) ? wreg[d][i].z : wreg[d][i].w;
                acc[d][0] = fmaf(wv, a.x, acc[d][0]);
                acc[d][1] = fmaf(wv, a.y, acc[d][1]);
                acc[d][2] = fmaf(wv, a.z, acc[d][2]);
                acc[d][3] = fmaf(wv, a.w, acc[d][3]);
              }
            }
          }
          #pragma unroll
          for (int d = 0; d < 4; ++d)
            *(float4*)(dmp + (4*q + d)*16 + 4*c) =
                make_float4(acc[d][0], acc[d][1], acc[d][2], acc[d][3]);
        }
      }
      __syncthreads();
      for (int task = tid; task < DOTS_T*16; task += 256) {
        int dot = task >> 4, s = task & 15;
        float sum = 0.0f;
        #pragma unroll
        for (int kq = 0; kq < 21; ++kq)
          sum += lds[L_DUMP + kq*TDP + dot*16 + s];
        lds[L_DUMP + dot*16 + s] = sum;     // compact gates
      }
      __syncthreads();
      if (tid < 160) {
        int uu = tid >> 4, b = tid & 15;
        if (uu < ucnt) {
          float gi = lds[L_DUMP + (0*UPB + uu)*16 + b];
          float gf = lds[L_DUMP + (1*UPB + uu)*16 + b];
          float gg = lds[L_DUMP + (2*UPB + uu)*16 + b];
          float go = lds[L_DUMP + (3*UPB + uu)*16 + b];
          tc_reg = sigf(gf)*tc_reg + sigf(gi)*tanhf(gg);
          float th = sigf(go)*tanhf(tc_reg);
          thbuf[((size_t)(t & 1)*HB + (b0 + b))*TK + (u0 + uu)] = th;
        }
      }
    }

    ++epoch;
    xbar(role, epoch, slots, flag, broken);   // th(t) visible

    // ---- P2 ----
    if (isE) {
      int p = t & 1;
      {
        int r = tid >> 4, lane = tid & 15;
        if (r < nred) {
          const float* thp = thbuf + ((size_t)p*HB + (b0 + redl[r]))*TK;
          #pragma unroll
          for (int i = 0; i < 4; ++i) {
            int k = lane + 16*i;
            lds[L_THL + r*65 + k] = thp[k];
          }
        }
      }
      __syncthreads();
      if (tid < 192) {
        int rr = tid / JPB, jj = tid % JPB;
        int j = e*JPB + jj;
        if (rr < nred) {
          int b = redl[rr];
          int sp = sptr[b];
          float* s2base = stack + ((size_t)((b0+b)*SQ + (sp-2)))*DW;
          const float* s1base = stack + ((size_t)((b0+b)*SQ + (sp-1)))*DW;
          float s2c = s2base[HD + j];
          float s1c = s1base[HD + j];
          float a0 = lds[L_DUMP + (0*JPB + jj)*16 + rr] + lds[L_BRED + 0*JPB + jj];
          float a1 = lds[L_DUMP + (1*JPB + jj)*16 + rr] + lds[L_BRED + 1*JPB + jj];
          float a2 = lds[L_DUMP + (2*JPB + jj)*16 + rr] + lds[L_BRED + 2*JPB + jj];
          float a3 = lds[L_DUMP + (3*JPB + jj)*16 + rr] + lds[L_BRED + 3*JPB + jj];
          float a4 = lds[L_DUMP + (4*JPB + jj)*16 + rr] + lds[L_BRED + 4*JPB + jj];
          #pragma unroll 8
          for (int k = 0; k < 64; ++k) {
            float tv = lds[L_THL + rr*65 + k];
            a0 = fmaf(tv, lds[L_WTR + (0*JPB + jj)*65 + k], a0);
            a1 = fmaf(tv, lds[L_WTR + (1*JPB + jj)*65 + k], a1);
            a2 = fmaf(tv, lds[L_WTR + (2*JPB + jj)*65 + k], a2);
            a3 = fmaf(tv, lds[L_WTR + (3*JPB + jj)*65 + k], a3);
            a4 = fmaf(tv, lds[L_WTR + (4*JPB + jj)*65 + k], a4);
          }
          float rc = sigf(a1)*s2c + sigf(a2)*s1c + sigf(a0)*tanhf(a4);
          float rh = sigf(a3)*tanhf(rc);
          s2base[j] = rh;
          s2base[HD + j] = rc;
        } else {
          int b = shl[rr - nred];
          int sp = sptr[b], bp = bptr[b];
          const float* src = bufs + ((size_t)((b0+b)*SQ + bp))*DW;
          float* dst = stack + ((size_t)((b0+b)*SQ + sp))*DW;
          dst[j] = src[j];
          dst[HD + j] = src[HD + j];
        }
      }
    } else if (role == NE) {   // logits
      if (tid < 32) {
        int b = tid >> 1, c = tid & 1;
        const float* th = thbuf + ((size_t)(t & 1)*HB + (b0 + b))*TK;
        float s = btrans[c];
        #pragma unroll 8
        for (int u = 0; u < TK; ++u) s = fmaf(th[u], Wtrans[u*2 + c], s);
        out[(size_t)(b0 + b)*OUTW + HD + 2*t + c] = s;
      }
    }

    __syncthreads();
    if (tid < 16) {
      if (!((w >> tid) & 1)) { sptr[tid] += 1; bptr[tid] += 1; }
      else                   { sptr[tid] -= 1; }
    }

    ++epoch;
    xbar(role, epoch, slots, flag, broken);   // stack(t) visible
  }

  // ---- final sentence encoding ----
  if (isE && tid < 192) {
    int b = tid / JPB, jj = tid % JPB;
    int j = e*JPB + jj;
    int sp = sptr[b] - 1; if (sp < 0) sp = 0;
    out[(size_t)(b0 + b)*OUTW + j] =
        stack[((size_t)((b0 + b)*SQ + sp))*DW + j];
  }
}

// ---------------------------------------------------------------------
extern "C" void kernel_launch(void* const* d_in, const int* in_sizes, int n_in,
                              void* d_out, int out_size, void* d_ws, size_t ws_size,
                              hipStream_t stream) {
  const float* bufs   = (const float*)d_in[0];
  const int*   trans  = (const int*)  d_in[1];
  const float* Wbuf   = (const float*)d_in[2];
  const float* Ws1    = (const float*)d_in[3];
  const float* Ws2    = (const float*)d_in[4];
  const float* Wih    = (const float*)d_in[5];
  const float* Whh    = (const float*)d_in[6];
  const float* Wtrans = (const float*)d_in[7];
  const float* btrans = (const float*)d_in[8];
  const float* Wl     = (const float*)d_in[9];
  const float* Wr     = (const float*)d_in[10];
  const float* Wtrk   = (const float*)d_in[11];
  const float* bredv  = (const float*)d_in[12];
  float* ws  = (float*)d_ws;
  float* out = (float*)d_out;

  if (ws_size < (size_t)WS_FLOATS * sizeof(float)) return;

  {
    int total = N_WCT + N_TH + N_BAR + 8*NSTEP;
    prep_a<<<(total + 255) / 256, 256, 0, stream>>>(Wbuf, Ws1, Ws2, trans, ws);
  }
  {
    int total = N_WEB + N_WTB + N_WTR;
    prep_b<<<(total + 255) / 256, 256, 0, stream>>>(Wih, Whh, Wl, Wr, Wtrk, ws);
  }
  (void)hipFuncSetAttribute((const void*)spinn_kernel,
                            hipFuncAttributeMaxDynamicSharedMemorySize, 160000);
  spinn_kernel<<<256, 256, LDS_FLOATS * sizeof(float), stream>>>(
      bufs, Wtrans, btrans, bredv, ws, out);
}

// Round 6
// 13156.778 us; speedup vs baseline: 1.6561x; 1.6561x over previous
//
#include <hip/hip_runtime.h>

// =====================================================================
// SPINN-style stack LSTM, MI355X.
// 8 groups (one per XCD via HW_REG_XCC_ID) x 16 batch; 32 blocks/group
// (25 "E" reduce-slice blocks x 12 dims, 7 "T" tracker blocks x 10
// units). R6: fp32 weights resident in VGPRs, with BOTH paths sized at
// exactly 160 wreg floats/thread (wreg[4][10]): E = 4 dots x 40k x 16
// slices (240 thr), T re-sliced from 21x48 to 25x40 (k padded 964->1000
// with zeros) = 4 dots x 40k x 25 slices (250 thr). R5 spilled because
// T's 192-float slice pushed peak regs past the 256 arch-VGPR file
// (VGPR=256 + 10GB scratch FETCH). Unified act layout 25x41x20.
// Barrier: relaxed agent-scope atomic polls + one buffer_inv.
// 1 block/CU forced via 149KB LDS.
// =====================================================================

#define NSTEP 511
#define HB 128
#define SQ 256
#define HD 300
#define DW 600
#define TK 64

#define NB 16
#define NE 25           // E blocks per group
#define JPB 12          // j dims per E block
#define DOTS_E 60       // 5 gates * 12 j
#define KE 640          // padded 600
#define UPB 10
#define DOTS_T 40       // 4 gates * 10 units
#define KT2 1000        // padded 964 (900 fused + 64 hh + 36 zero)
#define ASTR 20         // act row stride (floats), 16 slots + pad
#define SLP 820         // act slice pitch = 41 rows * ASTR
#define OUTW 1322

// ---- workspace layout (floats) ----
#define N_WEB 960000            // 25*60*640   E weight slices fp32
#define N_WTB 280000            // 7*40*1000   T fused weight slices fp32
#define N_WTR 97500             // 25*60*65    W_track slices
#define N_TH  16384             // 2*128*64    th double buffer
#define N_STACK 19660800        // 128*256*600
#define N_BAR 1024
#define N_TPK 4096
#define N_WCT 230400            // WcatT (prep only, overlaps stack)

#define OFF_WEB 0
#define OFF_WTB 960000
#define OFF_WTR 1240000
#define OFF_TH  1337504
#define OFF_STACK 1353888
#define OFF_BAR 21014688
#define OFF_TPK 21015712
#define WS_FLOATS 21019808
#define OFF_WCT OFF_STACK

// ---- LDS layout (floats) ----
#define L_ACT 0                 // 25 slices * SLP = 20500
#define L_DUMP 20500            // E: 8*EDP=7712 ; T: 25*TDP=16100
#define EDP 964                 // E dump kq pitch (60*16 + 4 skew)
#define TDP 644                 // T dump kq pitch (40*16 + 4 skew)
#define L_WTR 28212             // (E only, after E dump) 60*65 = 3900
#define L_THL 32112             // 16*65 = 1040
#define L_BRED 33152            // 60(+pad)
#define L_TRW 36600             // (after T dump) 511 ints (+1)
#define L_INT 37112             // 96 ints
#define LDS_FLOATS 37208        // 148832 B (>80KB => 1 block/CU)

__device__ __forceinline__ float sigf(float x) { return 1.0f / (1.0f + __expf(-x)); }

// ---------------------------------------------------------------------
// prep_a: WcatT[256][900], zero th/barrier, pack transitions.
// ---------------------------------------------------------------------
__global__ void prep_a(const float* __restrict__ Wbuf, const float* __restrict__ Ws1,
                       const float* __restrict__ Ws2, const int* __restrict__ trans,
                       float* __restrict__ ws) {
  int idx = blockIdx.x * 256 + threadIdx.x;
  if (idx < N_WCT) {
    int k = idx % 900;
    int m = idx / 900;
    float v = (k < 300) ? Wbuf[k*256 + m]
            : (k < 600) ? Ws1[(k-300)*256 + m]
                        : Ws2[(k-600)*256 + m];
    ws[OFF_WCT + idx] = v;
    return;
  }
  idx -= N_WCT;
  if (idx < N_TH) { ws[OFF_TH + idx] = 0.0f; return; }
  idx -= N_TH;
  if (idx < N_BAR) { ws[OFF_BAR + idx] = 0.0f; return; }
  idx -= N_BAR;
  if (idx < 8*NSTEP) {
    int g = idx / NSTEP, t = idx % NSTEP;
    int w = 0;
    #pragma unroll
    for (int b = 0; b < 16; ++b)
      w |= (trans[(size_t)(g*16 + b)*NSTEP + t] & 1) << b;
    ((int*)(ws + OFF_TPK))[g*NSTEP + t] = w;
  }
}

// ---------------------------------------------------------------------
// prep_b: fp32 transposed weight slices; tracker input projection fused
// with W_ih: WT[col][k<900] = sum_m Wcat[k][m] * W_ih[col][m]  (exact).
// T k-layout: 0..899 fused input proj, 900..963 Whh, 964..999 zero pad.
// ---------------------------------------------------------------------
__global__ void prep_b(const float* __restrict__ Wih, const float* __restrict__ Whh,
                       const float* __restrict__ Wl, const float* __restrict__ Wr,
                       const float* __restrict__ Wtrk, float* __restrict__ ws) {
  int idx = blockIdx.x * 256 + threadIdx.x;
  if (idx < N_WEB) {
    int k = idx % KE; int rest = idx / KE;
    int dot = rest % DOTS_E; int e = rest / DOTS_E;
    int g = dot / JPB, jj = dot % JPB;
    int col = g*HD + e*JPB + jj;
    float v = 0.0f;
    if (k < 300)      v = Wl[k*1500 + col];          // s2h @ W_left
    else if (k < 600) v = Wr[(k-300)*1500 + col];    // s1h @ W_right
    ws[OFF_WEB + idx] = v;
    return;
  }
  idx -= N_WEB;
  if (idx < N_WTB) {
    int k = idx % KT2; int rest = idx / KT2;
    int dot = rest % DOTS_T; int tb = rest / DOTS_T;
    int g = dot / UPB, uu = dot % UPB;
    int ucnt = (tb == 6) ? 10 : 9;
    float v = 0.0f;
    if (uu < ucnt) {
      int col = g*TK + tb*9 + uu;
      if (k < 900) {
        const float* wct = ws + OFF_WCT;
        const float* wi  = Wih + col*256;
        float s = 0.0f;
        #pragma unroll 4
        for (int m = 0; m < 256; ++m) s = fmaf(wct[m*900 + k], wi[m], s);
        v = s;
      } else if (k < 964) {
        v = Whh[col*TK + (k - 900)];
      }
    }
    ws[OFF_WTB + idx] = v;
    return;
  }
  idx -= N_WTB;
  if (idx < N_WTR) {
    int k = idx % 65; int rest = idx / 65;
    int dot = rest % DOTS_E; int e = rest / DOTS_E;
    int g = dot / JPB, jj = dot % JPB;
    ws[OFF_WTR + idx] = (k < 64) ? Wtrk[k*1500 + (g*HD + e*JPB + jj)] : 0.0f;
  }
}

// ---------------------------------------------------------------------
// XCD-local barrier. Data committed to L2 by the vmcnt(0) drain in
// __syncthreads(); polls are relaxed agent atomics (bypass L1); one
// post-barrier buffer_inv refreshes L1 for normal loads.
// ---------------------------------------------------------------------
__device__ __forceinline__ void xbar(int role, unsigned epoch,
                                     unsigned* slots, unsigned* flag,
                                     volatile int* broken) {
  __syncthreads();
  if (role == 0) {
    if (threadIdx.x < 64) {
      int lane = threadIdx.x;
      unsigned spins = 0;
      for (;;) {
        if (*broken) break;
        unsigned v = (lane >= 1 && lane < 32)
            ? __hip_atomic_load(slots + lane, __ATOMIC_RELAXED, __HIP_MEMORY_SCOPE_AGENT)
            : epoch;
        if (__all(v >= epoch)) break;
        __builtin_amdgcn_s_sleep(1);
        if (++spins > 4000000u) { if (lane == 0) *broken = 1; break; }
      }
      if (lane == 0)
        __hip_atomic_store(flag, epoch, __ATOMIC_RELAXED, __HIP_MEMORY_SCOPE_AGENT);
    }
  } else if (threadIdx.x == 0) {
    __hip_atomic_store(slots + role, epoch, __ATOMIC_RELAXED, __HIP_MEMORY_SCOPE_AGENT);
    unsigned spins = 0;
    while (!*broken &&
           __hip_atomic_load(flag, __ATOMIC_RELAXED, __HIP_MEMORY_SCOPE_AGENT) < epoch) {
      __builtin_amdgcn_s_sleep(1);
      if (++spins > 4000000u) *broken = 1;
    }
  }
  __syncthreads();
  asm volatile("buffer_inv" ::: "memory");
}

// ---------------------------------------------------------------------
// main persistent kernel: 256 blocks, 256 threads, 1 block/CU.
// ---------------------------------------------------------------------
__launch_bounds__(256, 1)
__global__ void spinn_kernel(const float* __restrict__ bufs,
                             const float* __restrict__ Wtrans, const float* __restrict__ btrans,
                             const float* __restrict__ bredv,
                             float* __restrict__ ws, float* __restrict__ out) {
  extern __shared__ float lds[];
  int* ibuf = (int*)(lds + L_INT);
  int* redl = ibuf + 16;
  int* shl  = ibuf + 32;
  int* sptr = ibuf + 48;
  int* bptr = ibuf + 64;
  volatile int* broken = ibuf + 82;
  int* role_s = ibuf + 90;
  int* trw = (int*)(lds + L_TRW);

  const int tid = threadIdx.x;

  // ---- runtime XCD-local grouping ----
  unsigned xcc;
  asm volatile("s_getreg_b32 %0, hwreg(HW_REG_XCC_ID)" : "=s"(xcc));
  xcc &= 7u;
  if (tid == 0) {
    unsigned slot = __hip_atomic_fetch_add((unsigned*)(ws + OFF_BAR) + 512 + xcc, 1u,
                                           __ATOMIC_RELAXED, __HIP_MEMORY_SCOPE_AGENT);
    *role_s = (int)slot;
    *broken = 0;
  }
  __syncthreads();
  const int role = *role_s;
  const int group = (int)xcc;
  if (role >= 32) return;

  const int b0 = group * NB;
  const bool isE = (role < NE);
  const int e  = role;
  const int tb = role - NE;
  const int u0 = (tb >= 0) ? tb*9 : 0;
  const int ucnt = (tb == 6) ? 10 : 9;

  unsigned* slots = (unsigned*)(ws + OFF_BAR) + (size_t)group*64;
  unsigned* flag  = slots + 32;

  float* stack = ws + OFF_STACK;
  float* thbuf = ws + OFF_TH;

  float tc_reg = 0.0f;

  // ---- preload this thread's fp32 weight slice into VGPRs (whole run) ----
  // BOTH paths: wreg[4][10] = 160 VGPRs (R5 lesson: T at 192 spilled).
  float4 wreg[4][10];
  if (isE) {
    if (tid < 240) {
      const int q = tid >> 4, kq = tid & 15;
      const float* wb = ws + OFF_WEB;
      #pragma unroll
      for (int d = 0; d < 4; ++d)
        #pragma unroll
        for (int i = 0; i < 10; ++i)
          wreg[d][i] = *(const float4*)(wb + (size_t)(e*DOTS_E + 4*q + d)*KE + kq*40 + 4*i);
    }
  } else {
    if (tid < 250) {
      const int q = tid / 25, kq = tid % 25;
      const float* wb = ws + OFF_WTB;
      #pragma unroll
      for (int d = 0; d < 4; ++d)
        #pragma unroll
        for (int i = 0; i < 10; ++i)
          wreg[d][i] = *(const float4*)(wb + (size_t)(tb*DOTS_T + 4*q + d)*KT2 + kq*40 + 4*i);
    }
  }

  // ---- one-time init ----
  if (tid < 16) { sptr[tid] = 0; bptr[tid] = 0; }
  for (int i = tid; i < NSTEP; i += 256)
    trw[i] = ((const int*)(ws + OFF_TPK))[group*NSTEP + i];
  if (isE) {
    for (int i = tid; i < DOTS_E*65; i += 256)
      lds[L_WTR + i] = ws[OFF_WTR + (size_t)e*DOTS_E*65 + i];
    for (int i = tid; i < DOTS_E; i += 256)
      lds[L_BRED + i] = bredv[(i/JPB)*HD + e*JPB + (i%JPB)];
    for (int i = tid; i < 800; i += 256) lds[615*ASTR + i] = 0.0f;   // k 600..639
  } else {
    for (int i = tid; i < 720; i += 256) lds[988*ASTR + i] = 0.0f;   // k 964..999
  }
  __syncthreads();

  unsigned epoch = 0;

  for (int t = 0; t < NSTEP; ++t) {
    // ---- prologue: transition word + compact lists ----
    const int w = trw[t] & 0xFFFF;          // bit=1 -> reduce
    const int nred = __popc(w);
    if (tid < 16) {
      int rank = __popc(w & ((1u << tid) - 1u));
      if ((w >> tid) & 1) redl[rank] = tid; else shl[tid - rank] = tid;
    }
    __syncthreads();

    // ---- P1 staging into LDS (fp32; row(k) = (k/40)*41 + k%40) ----
    if (isE) {
      int r = tid >> 4, lane = tid & 15;
      if (r < nred) {
        int b = redl[r];
        int sp = sptr[b];
        const float* s2p = stack + ((size_t)((b0+b)*SQ + sp-2))*DW;
        const float* s1p = stack + ((size_t)((b0+b)*SQ + sp-1))*DW;
        #pragma unroll 4
        for (int i = 0; i < 10; ++i) {
          int ch = lane + 16*i;
          if (ch < 150) {
            int sec = ch / 75, kc = ch % 75;
            int dim = kc*4;
            const float* src = (sec == 0) ? s2p : s1p;
            float4 v = *(const float4*)(src + dim);
            int kbase = sec*300 + dim;
            int row0 = (kbase/40)*41 + (kbase%40);
            lds[(row0+0)*ASTR + r] = v.x;
            lds[(row0+1)*ASTR + r] = v.y;
            lds[(row0+2)*ASTR + r] = v.z;
            lds[(row0+3)*ASTR + r] = v.w;
          }
        }
      }
    } else {
      {
        int b = tid >> 4, lane = tid & 15;
        int bp = bptr[b]; if (bp > SQ-1) bp = SQ-1;
        int sp = sptr[b];
        const float* bsrc = bufs + ((size_t)((b0+b)*SQ + bp))*DW;
        const float* s1p = (sp >= 1) ? stack + ((size_t)((b0+b)*SQ + sp-1))*DW : nullptr;
        const float* s2p = (sp >= 2) ? stack + ((size_t)((b0+b)*SQ + sp-2))*DW : nullptr;
        #pragma unroll 4
        for (int i = 0; i < 15; ++i) {
          int ch = lane + 16*i;
          if (ch < 225) {
            int sec = ch / 75, kc = ch % 75;
            int dim = kc*4;
            const float* src = (sec == 0) ? bsrc : ((sec == 1) ? s1p : s2p);
            float4 v = make_float4(0.f, 0.f, 0.f, 0.f);
            if (src) v = *(const float4*)(src + dim);
            int kbase = sec*300 + dim;
            int row0 = (kbase/40)*41 + (kbase%40);
            lds[(row0+0)*ASTR + b] = v.x;
            lds[(row0+1)*ASTR + b] = v.y;
            lds[(row0+2)*ASTR + b] = v.z;
            lds[(row0+3)*ASTR + b] = v.w;
          }
        }
      }
      { // th(t-1) -> k 900..963 ; t=0 reads zeroed parity-1 buffer
        int pm = (t - 1) & 1;
        int b = tid >> 4, uc = tid & 15;
        float4 v = *(const float4*)(thbuf + ((size_t)pm*HB + (b0+b))*TK + uc*4);
        float vv[4] = {v.x, v.y, v.z, v.w};
        #pragma unroll
        for (int l = 0; l < 4; ++l) {
          int k = 900 + uc*4 + l;
          int row = (k/40)*41 + (k%40);
          lds[row*ASTR + b] = vv[l];
        }
      }
    }
    __syncthreads();

    // ---- P1 compute (weights from VGPRs, chunked acc[4][4]) ----
    if (isE) {
      const int nchunk = (nred + 3) >> 2;
      if (nchunk > 0) {
        if (tid < 240) {
          const int q = tid >> 4, kq = tid & 15;
          const float* ab = lds + kq*SLP;
          float* dmp = lds + L_DUMP;
          #pragma unroll 1
          for (int c = 0; c < nchunk; ++c) {
            float acc[4][4];
            #pragma unroll
            for (int d = 0; d < 4; ++d)
              #pragma unroll
              for (int s = 0; s < 4; ++s) acc[d][s] = 0.0f;
            #pragma unroll
            for (int i = 0; i < 10; ++i) {
              #pragma unroll
              for (int kk = 0; kk < 4; ++kk) {
                float4 a = *(const float4*)(ab + (4*i + kk)*ASTR + 4*c);
                #pragma unroll
                for (int d = 0; d < 4; ++d) {
                  float wv = (kk == 0) ? wreg[d][i].x : (kk == 1) ? wreg[d][i].y
                           : (kk == 2) ? wreg[d][i].z : wreg[d][i].w;
                  acc[d][0] = fmaf(wv, a.x, acc[d][0]);
                  acc[d][1] = fmaf(wv, a.y, acc[d][1]);
                  acc[d][2] = fmaf(wv, a.z, acc[d][2]);
                  acc[d][3] = fmaf(wv, a.w, acc[d][3]);
                }
              }
            }
            // pair-reduce kq <-> kq^8 in-register (same q, stays in-wave)
            #pragma unroll
            for (int d = 0; d < 4; ++d)
              #pragma unroll
              for (int s = 0; s < 4; ++s)
                acc[d][s] += __shfl_xor(acc[d][s], 8, 64);
            if (kq < 8) {
              #pragma unroll
              for (int d = 0; d < 4; ++d)
                *(float4*)(dmp + kq*EDP + (4*q + d)*16 + 4*c) =
                    make_float4(acc[d][0], acc[d][1], acc[d][2], acc[d][3]);
            }
          }
        }
        __syncthreads();
        for (int task = tid; task < DOTS_E*16; task += 256) {
          int dot = task >> 4, s = task & 15;
          float sum = 0.0f;
          #pragma unroll
          for (int kq = 0; kq < 8; ++kq)
            sum += lds[L_DUMP + kq*EDP + dot*16 + s];
          lds[L_DUMP + dot*16 + s] = sum;   // compact a_red (left+right parts)
        }
      }
    } else {
      if (tid < 250) {
        const int q = tid / 25, kq = tid % 25;
        const float* ab = lds + kq*SLP;
        float* dmp = lds + L_DUMP + kq*TDP;
        #pragma unroll 1
        for (int c = 0; c < 4; ++c) {
          float acc[4][4];
          #pragma unroll
          for (int d = 0; d < 4; ++d)
            #pragma unroll
            for (int s = 0; s < 4; ++s) acc[d][s] = 0.0f;
          #pragma unroll
          for (int i = 0; i < 10; ++i) {
            #pragma unroll
            for (int kk = 0; kk < 4; ++kk) {
              float4 a = *(const float4*)(ab + (4*i + kk)*ASTR + 4*c);
              #pragma unroll
              for (int d = 0; d < 4; ++d) {
                float wv = (kk == 0) ? wreg[d][i].x : (kk == 1) ? wreg[d][i].y
                         : (kk == 2) ? wreg[d][i].z : wreg[d][i].w;
                acc[d][0] = fmaf(wv, a.x, acc[d][0]);
                acc[d][1] = fmaf(wv, a.y, acc[d][1]);
                acc[d][2] = fmaf(wv, a.z, acc[d][2]);
                acc[d][3] = fmaf(wv, a.w, acc[d][3]);
              }
            }
          }
          #pragma unroll
          for (int d = 0; d < 4; ++d)
            *(float4*)(dmp + (4*q + d)*16 + 4*c) =
                make_float4(acc[d][0], acc[d][1], acc[d][2], acc[d][3]);
        }
      }
      __syncthreads();
      for (int task = tid; task < DOTS_T*16; task += 256) {
        int dot = task >> 4, s = task & 15;
        float sum = 0.0f;
        #pragma unroll
        for (int kq = 0; kq < 25; ++kq)
          sum += lds[L_DUMP + kq*TDP + dot*16 + s];
        lds[L_DUMP + dot*16 + s] = sum;     // compact gates
      }
      __syncthreads();
      if (tid < 160) {
        int uu = tid >> 4, b = tid & 15;
        if (uu < ucnt) {
          float gi = lds[L_DUMP + (0*UPB + uu)*16 + b];
          float gf = lds[L_DUMP + (1*UPB + uu)*16 + b];
          float gg = lds[L_DUMP + (2*UPB + uu)*16 + b];
          float go = lds[L_DUMP + (3*UPB + uu)*16 + b];
          tc_reg = sigf(gf)*tc_reg + sigf(gi)*tanhf(gg);
          float th = sigf(go)*tanhf(tc_reg);
          thbuf[((size_t)(t & 1)*HB + (b0 + b))*TK + (u0 + uu)] = th;
        }
      }
    }

    ++epoch;
    xbar(role, epoch, slots, flag, broken);   // th(t) visible

    // ---- P2 ----
    if (isE) {
      int p = t & 1;
      {
        int r = tid >> 4, lane = tid & 15;
        if (r < nred) {
          const float* thp = thbuf + ((size_t)p*HB + (b0 + redl[r]))*TK;
          #pragma unroll
          for (int i = 0; i < 4; ++i) {
            int k = lane + 16*i;
            lds[L_THL + r*65 + k] = thp[k];
          }
        }
      }
      __syncthreads();
      if (tid < 192) {
        int rr = tid / JPB, jj = tid % JPB;
        int j = e*JPB + jj;
        if (rr < nred) {
          int b = redl[rr];
          int sp = sptr[b];
          float* s2base = stack + ((size_t)((b0+b)*SQ + (sp-2)))*DW;
          const float* s1base = stack + ((size_t)((b0+b)*SQ + (sp-1)))*DW;
          float s2c = s2base[HD + j];
          float s1c = s1base[HD + j];
          float a0 = lds[L_DUMP + (0*JPB + jj)*16 + rr] + lds[L_BRED + 0*JPB + jj];
          float a1 = lds[L_DUMP + (1*JPB + jj)*16 + rr] + lds[L_BRED + 1*JPB + jj];
          float a2 = lds[L_DUMP + (2*JPB + jj)*16 + rr] + lds[L_BRED + 2*JPB + jj];
          float a3 = lds[L_DUMP + (3*JPB + jj)*16 + rr] + lds[L_BRED + 3*JPB + jj];
          float a4 = lds[L_DUMP + (4*JPB + jj)*16 + rr] + lds[L_BRED + 4*JPB + jj];
          #pragma unroll 8
          for (int k = 0; k < 64; ++k) {
            float tv = lds[L_THL + rr*65 + k];
            a0 = fmaf(tv, lds[L_WTR + (0*JPB + jj)*65 + k], a0);
            a1 = fmaf(tv, lds[L_WTR + (1*JPB + jj)*65 + k], a1);
            a2 = fmaf(tv, lds[L_WTR + (2*JPB + jj)*65 + k], a2);
            a3 = fmaf(tv, lds[L_WTR + (3*JPB + jj)*65 + k], a3);
            a4 = fmaf(tv, lds[L_WTR + (4*JPB + jj)*65 + k], a4);
          }
          float rc = sigf(a1)*s2c + sigf(a2)*s1c + sigf(a0)*tanhf(a4);
          float rh = sigf(a3)*tanhf(rc);
          s2base[j] = rh;
          s2base[HD + j] = rc;
        } else {
          int b = shl[rr - nred];
          int sp = sptr[b], bp = bptr[b];
          const float* src = bufs + ((size_t)((b0+b)*SQ + bp))*DW;
          float* dst = stack + ((size_t)((b0+b)*SQ + sp))*DW;
          dst[j] = src[j];
          dst[HD + j] = src[HD + j];
        }
      }
    } else if (role == NE) {   // logits
      if (tid < 32) {
        int b = tid >> 1, c = tid & 1;
        const float* th = thbuf + ((size_t)(t & 1)*HB + (b0 + b))*TK;
        float s = btrans[c];
        #pragma unroll 8
        for (int u = 0; u < TK; ++u) s = fmaf(th[u], Wtrans[u*2 + c], s);
        out[(size_t)(b0 + b)*OUTW + HD + 2*t + c] = s;
      }
    }

    __syncthreads();
    if (tid < 16) {
      if (!((w >> tid) & 1)) { sptr[tid] += 1; bptr[tid] += 1; }
      else                   { sptr[tid] -= 1; }
    }

    ++epoch;
    xbar(role, epoch, slots, flag, broken);   // stack(t) visible
  }

  // ---- final sentence encoding ----
  if (isE && tid < 192) {
    int b = tid / JPB, jj = tid % JPB;
    int j = e*JPB + jj;
    int sp = sptr[b] - 1; if (sp < 0) sp = 0;
    out[(size_t)(b0 + b)*OUTW + j] =
        stack[((size_t)((b0 + b)*SQ + sp))*DW + j];
  }
}

// ---------------------------------------------------------------------
extern "C" void kernel_launch(void* const* d_in, const int* in_sizes, int n_in,
                              void* d_out, int out_size, void* d_ws, size_t ws_size,
                              hipStream_t stream) {
  const float* bufs   = (const float*)d_in[0];
  const int*   trans  = (const int*)  d_in[1];
  const float* Wbuf   = (const float*)d_in[2];
  const float* Ws1    = (const float*)d_in[3];
  const float* Ws2    = (const float*)d_in[4];
  const float* Wih    = (const float*)d_in[5];
  const float* Whh    = (const float*)d_in[6];
  const float* Wtrans = (const float*)d_in[7];
  const float* btrans = (const float*)d_in[8];
  const float* Wl     = (const float*)d_in[9];
  const float* Wr     = (const float*)d_in[10];
  const float* Wtrk   = (const float*)d_in[11];
  const float* bredv  = (const float*)d_in[12];
  float* ws  = (float*)d_ws;
  float* out = (float*)d_out;

  if (ws_size < (size_t)WS_FLOATS * sizeof(float)) return;

  {
    int total = N_WCT + N_TH + N_BAR + 8*NSTEP;
    prep_a<<<(total + 255) / 256, 256, 0, stream>>>(Wbuf, Ws1, Ws2, trans, ws);
  }
  {
    int total = N_WEB + N_WTB + N_WTR;
    prep_b<<<(total + 255) / 256, 256, 0, stream>>>(Wih, Whh, Wl, Wr, Wtrk, ws);
  }
  (void)hipFuncSetAttribute((const void*)spinn_kernel,
                            hipFuncAttributeMaxDynamicSharedMemorySize, 160000);
  spinn_kernel<<<256, 256, LDS_FLOATS * sizeof(float), stream>>>(
      bufs, Wtrans, btrans, bredv, ws, out);
}

// Round 7
// 13024.521 us; speedup vs baseline: 1.6729x; 1.0102x over previous
//
#include <hip/hip_runtime.h>

// =====================================================================
// SPINN-style stack LSTM, MI355X.
// 8 groups (one per XCD via HW_REG_XCC_ID) x 16 batch; 32 blocks/group
// (25 "E" reduce-slice blocks x 12 dims, 7 "T" tracker blocks x 10
// units). fp32 weights resident in VGPRs (wreg[4][10] = 160 regs both
// paths; R5 lesson: 192 spilled). R7: barrier polls reverted to R2's
// volatile loads + L1-only buffer_inv (XCD-local L2). R6's relaxed
// AGENT-scope atomic polls executed at the cross-XCD fabric coherence
// point (~700cy each, 31 serialized in the leader gather) = ~10us per
// barrier = the 23us/step stall (FETCH was already collapsed to 240MB).
// No agent-scope ops in the hot loop. 1 block/CU via 149KB LDS.
// =====================================================================

#define NSTEP 511
#define HB 128
#define SQ 256
#define HD 300
#define DW 600
#define TK 64

#define NB 16
#define NE 25           // E blocks per group
#define JPB 12          // j dims per E block
#define DOTS_E 60       // 5 gates * 12 j
#define KE 640          // padded 600
#define UPB 10
#define DOTS_T 40       // 4 gates * 10 units
#define KT2 1000        // padded 964 (900 fused + 64 hh + 36 zero)
#define ASTR 20         // act row stride (floats), 16 slots + pad
#define SLP 820         // act slice pitch = 41 rows * ASTR
#define OUTW 1322

// ---- workspace layout (floats) ----
#define N_WEB 960000            // 25*60*640   E weight slices fp32
#define N_WTB 280000            // 7*40*1000   T fused weight slices fp32
#define N_WTR 97500             // 25*60*65    W_track slices
#define N_TH  16384             // 2*128*64    th double buffer
#define N_STACK 19660800        // 128*256*600
#define N_BAR 1024
#define N_TPK 4096
#define N_WCT 230400            // WcatT (prep only, overlaps stack)

#define OFF_WEB 0
#define OFF_WTB 960000
#define OFF_WTR 1240000
#define OFF_TH  1337504
#define OFF_STACK 1353888
#define OFF_BAR 21014688
#define OFF_TPK 21015712
#define WS_FLOATS 21019808
#define OFF_WCT OFF_STACK

// ---- LDS layout (floats) ----
#define L_ACT 0                 // 25 slices * SLP = 20500
#define L_DUMP 20500            // E: 8*EDP=7712 ; T: 25*TDP=16100
#define EDP 964                 // E dump kq pitch (60*16 + 4 skew)
#define TDP 644                 // T dump kq pitch (40*16 + 4 skew)
#define L_WTR 28212             // (E only, after E dump) 60*65 = 3900
#define L_THL 32112             // 16*65 = 1040
#define L_BRED 33152            // 60(+pad)
#define L_TRW 36600             // (after T dump) 511 ints (+1)
#define L_INT 37112             // 96 ints
#define LDS_FLOATS 37208        // 148832 B (>80KB => 1 block/CU)

__device__ __forceinline__ float sigf(float x) { return 1.0f / (1.0f + __expf(-x)); }

// ---------------------------------------------------------------------
// prep_a: WcatT[256][900], zero th/barrier, pack transitions.
// ---------------------------------------------------------------------
__global__ void prep_a(const float* __restrict__ Wbuf, const float* __restrict__ Ws1,
                       const float* __restrict__ Ws2, const int* __restrict__ trans,
                       float* __restrict__ ws) {
  int idx = blockIdx.x * 256 + threadIdx.x;
  if (idx < N_WCT) {
    int k = idx % 900;
    int m = idx / 900;
    float v = (k < 300) ? Wbuf[k*256 + m]
            : (k < 600) ? Ws1[(k-300)*256 + m]
                        : Ws2[(k-600)*256 + m];
    ws[OFF_WCT + idx] = v;
    return;
  }
  idx -= N_WCT;
  if (idx < N_TH) { ws[OFF_TH + idx] = 0.0f; return; }
  idx -= N_TH;
  if (idx < N_BAR) { ws[OFF_BAR + idx] = 0.0f; return; }
  idx -= N_BAR;
  if (idx < 8*NSTEP) {
    int g = idx / NSTEP, t = idx % NSTEP;
    int w = 0;
    #pragma unroll
    for (int b = 0; b < 16; ++b)
      w |= (trans[(size_t)(g*16 + b)*NSTEP + t] & 1) << b;
    ((int*)(ws + OFF_TPK))[g*NSTEP + t] = w;
  }
}

// ---------------------------------------------------------------------
// prep_b: fp32 transposed weight slices; tracker input projection fused
// with W_ih: WT[col][k<900] = sum_m Wcat[k][m] * W_ih[col][m]  (exact).
// T k-layout: 0..899 fused input proj, 900..963 Whh, 964..999 zero pad.
// ---------------------------------------------------------------------
__global__ void prep_b(const float* __restrict__ Wih, const float* __restrict__ Whh,
                       const float* __restrict__ Wl, const float* __restrict__ Wr,
                       const float* __restrict__ Wtrk, float* __restrict__ ws) {
  int idx = blockIdx.x * 256 + threadIdx.x;
  if (idx < N_WEB) {
    int k = idx % KE; int rest = idx / KE;
    int dot = rest % DOTS_E; int e = rest / DOTS_E;
    int g = dot / JPB, jj = dot % JPB;
    int col = g*HD + e*JPB + jj;
    float v = 0.0f;
    if (k < 300)      v = Wl[k*1500 + col];          // s2h @ W_left
    else if (k < 600) v = Wr[(k-300)*1500 + col];    // s1h @ W_right
    ws[OFF_WEB + idx] = v;
    return;
  }
  idx -= N_WEB;
  if (idx < N_WTB) {
    int k = idx % KT2; int rest = idx / KT2;
    int dot = rest % DOTS_T; int tb = rest / DOTS_T;
    int g = dot / UPB, uu = dot % UPB;
    int ucnt = (tb == 6) ? 10 : 9;
    float v = 0.0f;
    if (uu < ucnt) {
      int col = g*TK + tb*9 + uu;
      if (k < 900) {
        const float* wct = ws + OFF_WCT;
        const float* wi  = Wih + col*256;
        float s = 0.0f;
        #pragma unroll 4
        for (int m = 0; m < 256; ++m) s = fmaf(wct[m*900 + k], wi[m], s);
        v = s;
      } else if (k < 964) {
        v = Whh[col*TK + (k - 900)];
      }
    }
    ws[OFF_WTB + idx] = v;
    return;
  }
  idx -= N_WTB;
  if (idx < N_WTR) {
    int k = idx % 65; int rest = idx / 65;
    int dot = rest % DOTS_E; int e = rest / DOTS_E;
    int g = dot / JPB, jj = dot % JPB;
    ws[OFF_WTR + idx] = (k < 64) ? Wtrk[k*1500 + (g*HD + e*JPB + jj)] : 0.0f;
  }
}

// ---------------------------------------------------------------------
// fence-free XCD-local barrier (R2 design, empirically correct).
// Data stores are committed to the XCD's L2 by the vmcnt(0) drain inside
// __syncthreads(); slot/flag are single-writer volatile words in the same
// L2; polls are normal coalesced loads (lanes 1..31 -> one L2 access)
// refreshed by an L1-only buffer_inv. NO agent-scope atomics here: those
// execute at the cross-XCD fabric coherence point (~700cy, serialized)
// and cost ~10us/barrier (the R6 stall).
// ---------------------------------------------------------------------
__device__ __forceinline__ void xbar(int role, unsigned epoch,
                                     volatile unsigned* slots, volatile unsigned* flag,
                                     volatile int* broken) {
  __syncthreads();                      // drains vmcnt on every wave
  if (role == 0) {
    if (threadIdx.x < 64) {             // leader wave: lanes 1..31 watch slots
      int lane = threadIdx.x;
      unsigned spins = 0;
      for (;;) {
        if (*broken) break;
        unsigned v = (lane >= 1 && lane < 32) ? slots[lane] : epoch;
        if (__all(v >= epoch)) break;
        __builtin_amdgcn_s_sleep(1);
        asm volatile("buffer_inv" ::: "memory");
        if (++spins > 2000000u) { if (lane == 0) *broken = 1; break; }
      }
      if (lane == 0) {
        *flag = epoch;
        asm volatile("s_waitcnt vmcnt(0)" ::: "memory");
      }
    }
  } else if (threadIdx.x == 0) {
    slots[role] = epoch;
    asm volatile("s_waitcnt vmcnt(0)" ::: "memory");
    unsigned spins = 0;
    while (!*broken && *flag < epoch) {
      __builtin_amdgcn_s_sleep(1);
      asm volatile("buffer_inv" ::: "memory");
      if (++spins > 2000000u) *broken = 1;
    }
  }
  __syncthreads();
  asm volatile("buffer_inv" ::: "memory");   // every wave refreshes L1 view
}

// ---------------------------------------------------------------------
// main persistent kernel: 256 blocks, 256 threads, 1 block/CU.
// ---------------------------------------------------------------------
__launch_bounds__(256, 1)
__global__ void spinn_kernel(const float* __restrict__ bufs,
                             const float* __restrict__ Wtrans, const float* __restrict__ btrans,
                             const float* __restrict__ bredv,
                             float* __restrict__ ws, float* __restrict__ out) {
  extern __shared__ float lds[];
  int* ibuf = (int*)(lds + L_INT);
  int* redl = ibuf + 16;
  int* shl  = ibuf + 32;
  int* sptr = ibuf + 48;
  int* bptr = ibuf + 64;
  volatile int* broken = ibuf + 82;
  int* role_s = ibuf + 90;
  int* trw = (int*)(lds + L_TRW);

  const int tid = threadIdx.x;

  // ---- runtime XCD-local grouping (one-time; agent atomic is fine here) ----
  unsigned xcc;
  asm volatile("s_getreg_b32 %0, hwreg(HW_REG_XCC_ID)" : "=s"(xcc));
  xcc &= 7u;
  if (tid == 0) {
    unsigned slot = __hip_atomic_fetch_add((unsigned*)(ws + OFF_BAR) + 512 + xcc, 1u,
                                           __ATOMIC_RELAXED, __HIP_MEMORY_SCOPE_AGENT);
    *role_s = (int)slot;
    *broken = 0;
  }
  __syncthreads();
  const int role = *role_s;
  const int group = (int)xcc;
  if (role >= 32) return;

  const int b0 = group * NB;
  const bool isE = (role < NE);
  const int e  = role;
  const int tb = role - NE;
  const int u0 = (tb >= 0) ? tb*9 : 0;
  const int ucnt = (tb == 6) ? 10 : 9;

  volatile unsigned* slots = (volatile unsigned*)((unsigned*)(ws + OFF_BAR) + (size_t)group*64);
  volatile unsigned* flag  = slots + 32;

  float* stack = ws + OFF_STACK;
  float* thbuf = ws + OFF_TH;

  float tc_reg = 0.0f;

  // ---- preload this thread's fp32 weight slice into VGPRs (whole run) ----
  // BOTH paths: wreg[4][10] = 160 VGPRs (R5 lesson: T at 192 spilled).
  float4 wreg[4][10];
  if (isE) {
    if (tid < 240) {
      const int q = tid >> 4, kq = tid & 15;
      const float* wb = ws + OFF_WEB;
      #pragma unroll
      for (int d = 0; d < 4; ++d)
        #pragma unroll
        for (int i = 0; i < 10; ++i)
          wreg[d][i] = *(const float4*)(wb + (size_t)(e*DOTS_E + 4*q + d)*KE + kq*40 + 4*i);
    }
  } else {
    if (tid < 250) {
      const int q = tid / 25, kq = tid % 25;
      const float* wb = ws + OFF_WTB;
      #pragma unroll
      for (int d = 0; d < 4; ++d)
        #pragma unroll
        for (int i = 0; i < 10; ++i)
          wreg[d][i] = *(const float4*)(wb + (size_t)(tb*DOTS_T + 4*q + d)*KT2 + kq*40 + 4*i);
    }
  }

  // ---- one-time init ----
  if (tid < 16) { sptr[tid] = 0; bptr[tid] = 0; }
  for (int i = tid; i < NSTEP; i += 256)
    trw[i] = ((const int*)(ws + OFF_TPK))[group*NSTEP + i];
  if (isE) {
    for (int i = tid; i < DOTS_E*65; i += 256)
      lds[L_WTR + i] = ws[OFF_WTR + (size_t)e*DOTS_E*65 + i];
    for (int i = tid; i < DOTS_E; i += 256)
      lds[L_BRED + i] = bredv[(i/JPB)*HD + e*JPB + (i%JPB)];
    for (int i = tid; i < 800; i += 256) lds[615*ASTR + i] = 0.0f;   // k 600..639
  } else {
    for (int i = tid; i < 720; i += 256) lds[988*ASTR + i] = 0.0f;   // k 964..999
  }
  __syncthreads();

  unsigned epoch = 0;

  for (int t = 0; t < NSTEP; ++t) {
    // ---- prologue: transition word + compact lists ----
    const int w = trw[t] & 0xFFFF;          // bit=1 -> reduce
    const int nred = __popc(w);
    if (tid < 16) {
      int rank = __popc(w & ((1u << tid) - 1u));
      if ((w >> tid) & 1) redl[rank] = tid; else shl[tid - rank] = tid;
    }
    __syncthreads();

    // ---- P1 staging into LDS (fp32; row(k) = (k/40)*41 + k%40) ----
    if (isE) {
      int r = tid >> 4, lane = tid & 15;
      if (r < nred) {
        int b = redl[r];
        int sp = sptr[b];
        const float* s2p = stack + ((size_t)((b0+b)*SQ + sp-2))*DW;
        const float* s1p = stack + ((size_t)((b0+b)*SQ + sp-1))*DW;
        #pragma unroll 4
        for (int i = 0; i < 10; ++i) {
          int ch = lane + 16*i;
          if (ch < 150) {
            int sec = ch / 75, kc = ch % 75;
            int dim = kc*4;
            const float* src = (sec == 0) ? s2p : s1p;
            float4 v = *(const float4*)(src + dim);
            int kbase = sec*300 + dim;
            int row0 = (kbase/40)*41 + (kbase%40);
            lds[(row0+0)*ASTR + r] = v.x;
            lds[(row0+1)*ASTR + r] = v.y;
            lds[(row0+2)*ASTR + r] = v.z;
            lds[(row0+3)*ASTR + r] = v.w;
          }
        }
      }
    } else {
      {
        int b = tid >> 4, lane = tid & 15;
        int bp = bptr[b]; if (bp > SQ-1) bp = SQ-1;
        int sp = sptr[b];
        const float* bsrc = bufs + ((size_t)((b0+b)*SQ + bp))*DW;
        const float* s1p = (sp >= 1) ? stack + ((size_t)((b0+b)*SQ + sp-1))*DW : nullptr;
        const float* s2p = (sp >= 2) ? stack + ((size_t)((b0+b)*SQ + sp-2))*DW : nullptr;
        #pragma unroll 4
        for (int i = 0; i < 15; ++i) {
          int ch = lane + 16*i;
          if (ch < 225) {
            int sec = ch / 75, kc = ch % 75;
            int dim = kc*4;
            const float* src = (sec == 0) ? bsrc : ((sec == 1) ? s1p : s2p);
            float4 v = make_float4(0.f, 0.f, 0.f, 0.f);
            if (src) v = *(const float4*)(src + dim);
            int kbase = sec*300 + dim;
            int row0 = (kbase/40)*41 + (kbase%40);
            lds[(row0+0)*ASTR + b] = v.x;
            lds[(row0+1)*ASTR + b] = v.y;
            lds[(row0+2)*ASTR + b] = v.z;
            lds[(row0+3)*ASTR + b] = v.w;
          }
        }
      }
      { // th(t-1) -> k 900..963 ; t=0 reads zeroed parity-1 buffer
        int pm = (t - 1) & 1;
        int b = tid >> 4, uc = tid & 15;
        float4 v = *(const float4*)(thbuf + ((size_t)pm*HB + (b0+b))*TK + uc*4);
        float vv[4] = {v.x, v.y, v.z, v.w};
        #pragma unroll
        for (int l = 0; l < 4; ++l) {
          int k = 900 + uc*4 + l;
          int row = (k/40)*41 + (k%40);
          lds[row*ASTR + b] = vv[l];
        }
      }
    }
    __syncthreads();

    // ---- P1 compute (weights from VGPRs, chunked acc[4][4]) ----
    if (isE) {
      const int nchunk = (nred + 3) >> 2;
      if (nchunk > 0) {
        if (tid < 240) {
          const int q = tid >> 4, kq = tid & 15;
          const float* ab = lds + kq*SLP;
          float* dmp = lds + L_DUMP;
          #pragma unroll 1
          for (int c = 0; c < nchunk; ++c) {
            float acc[4][4];
            #pragma unroll
            for (int d = 0; d < 4; ++d)
              #pragma unroll
              for (int s = 0; s < 4; ++s) acc[d][s] = 0.0f;
            #pragma unroll
            for (int i = 0; i < 10; ++i) {
              #pragma unroll
              for (int kk = 0; kk < 4; ++kk) {
                float4 a = *(const float4*)(ab + (4*i + kk)*ASTR + 4*c);
                #pragma unroll
                for (int d = 0; d < 4; ++d) {
                  float wv = (kk == 0) ? wreg[d][i].x : (kk == 1) ? wreg[d][i].y
                           : (kk == 2) ? wreg[d][i].z : wreg[d][i].w;
                  acc[d][0] = fmaf(wv, a.x, acc[d][0]);
                  acc[d][1] = fmaf(wv, a.y, acc[d][1]);
                  acc[d][2] = fmaf(wv, a.z, acc[d][2]);
                  acc[d][3] = fmaf(wv, a.w, acc[d][3]);
                }
              }
            }
            // pair-reduce kq <-> kq^8 in-register (same q, stays in-wave)
            #pragma unroll
            for (int d = 0; d < 4; ++d)
              #pragma unroll
              for (int s = 0; s < 4; ++s)
                acc[d][s] += __shfl_xor(acc[d][s], 8, 64);
            if (kq < 8) {
              #pragma unroll
              for (int d = 0; d < 4; ++d)
                *(float4*)(dmp + kq*EDP + (4*q + d)*16 + 4*c) =
                    make_float4(acc[d][0], acc[d][1], acc[d][2], acc[d][3]);
            }
          }
        }
        __syncthreads();
        for (int task = tid; task < DOTS_E*16; task += 256) {
          int dot = task >> 4, s = task & 15;
          float sum = 0.0f;
          #pragma unroll
          for (int kq = 0; kq < 8; ++kq)
            sum += lds[L_DUMP + kq*EDP + dot*16 + s];
          lds[L_DUMP + dot*16 + s] = sum;   // compact a_red (left+right parts)
        }
      }
    } else {
      if (tid < 250) {
        const int q = tid / 25, kq = tid % 25;
        const float* ab = lds + kq*SLP;
        float* dmp = lds + L_DUMP + kq*TDP;
        #pragma unroll 1
        for (int c = 0; c < 4; ++c) {
          float acc[4][4];
          #pragma unroll
          for (int d = 0; d < 4; ++d)
            #pragma unroll
            for (int s = 0; s < 4; ++s) acc[d][s] = 0.0f;
          #pragma unroll
          for (int i = 0; i < 10; ++i) {
            #pragma unroll
            for (int kk = 0; kk < 4; ++kk) {
              float4 a = *(const float4*)(ab + (4*i + kk)*ASTR + 4*c);
              #pragma unroll
              for (int d = 0; d < 4; ++d) {
                float wv = (kk == 0) ? wreg[d][i].x : (kk == 1) ? wreg[d][i].y
                         : (kk == 2) ? wreg[d][i].z : wreg[d][i].w;
                acc[d][0] = fmaf(wv, a.x, acc[d][0]);
                acc[d][1] = fmaf(wv, a.y, acc[d][1]);
                acc[d][2] = fmaf(wv, a.z, acc[d][2]);
                acc[d][3] = fmaf(wv, a.w, acc[d][3]);
              }
            }
          }
          #pragma unroll
          for (int d = 0; d < 4; ++d)
            *(float4*)(dmp + (4*q + d)*16 + 4*c) =
                make_float4(acc[d][0], acc[d][1], acc[d][2], acc[d][3]);
        }
      }
      __syncthreads();
      for (int task = tid; task < DOTS_T*16; task += 256) {
        int dot = task >> 4, s = task & 15;
        float sum = 0.0f;
        #pragma unroll
        for (int kq = 0; kq < 25; ++kq)
          sum += lds[L_DUMP + kq*TDP + dot*16 + s];
        lds[L_DUMP + dot*16 + s] = sum;     // compact gates
      }
      __syncthreads();
      if (tid < 160) {
        int uu = tid >> 4, b = tid & 15;
        if (uu < ucnt) {
          float gi = lds[L_DUMP + (0*UPB + uu)*16 + b];
          float gf = lds[L_DUMP + (1*UPB + uu)*16 + b];
          float gg = lds[L_DUMP + (2*UPB + uu)*16 + b];
          float go = lds[L_DUMP + (3*UPB + uu)*16 + b];
          tc_reg = sigf(gf)*tc_reg + sigf(gi)*tanhf(gg);
          float th = sigf(go)*tanhf(tc_reg);
          thbuf[((size_t)(t & 1)*HB + (b0 + b))*TK + (u0 + uu)] = th;
        }
      }
    }

    ++epoch;
    xbar(role, epoch, slots, flag, broken);   // th(t) visible

    // ---- P2 ----
    if (isE) {
      int p = t & 1;
      {
        int r = tid >> 4, lane = tid & 15;
        if (r < nred) {
          const float* thp = thbuf + ((size_t)p*HB + (b0 + redl[r]))*TK;
          #pragma unroll
          for (int i = 0; i < 4; ++i) {
            int k = lane + 16*i;
            lds[L_THL + r*65 + k] = thp[k];
          }
        }
      }
      __syncthreads();
      if (tid < 192) {
        int rr = tid / JPB, jj = tid % JPB;
        int j = e*JPB + jj;
        if (rr < nred) {
          int b = redl[rr];
          int sp = sptr[b];
          float* s2base = stack + ((size_t)((b0+b)*SQ + (sp-2)))*DW;
          const float* s1base = stack + ((size_t)((b0+b)*SQ + (sp-1)))*DW;
          float s2c = s2base[HD + j];
          float s1c = s1base[HD + j];
          float a0 = lds[L_DUMP + (0*JPB + jj)*16 + rr] + lds[L_BRED + 0*JPB + jj];
          float a1 = lds[L_DUMP + (1*JPB + jj)*16 + rr] + lds[L_BRED + 1*JPB + jj];
          float a2 = lds[L_DUMP + (2*JPB + jj)*16 + rr] + lds[L_BRED + 2*JPB + jj];
          float a3 = lds[L_DUMP + (3*JPB + jj)*16 + rr] + lds[L_BRED + 3*JPB + jj];
          float a4 = lds[L_DUMP + (4*JPB + jj)*16 + rr] + lds[L_BRED + 4*JPB + jj];
          #pragma unroll 8
          for (int k = 0; k < 64; ++k) {
            float tv = lds[L_THL + rr*65 + k];
            a0 = fmaf(tv, lds[L_WTR + (0*JPB + jj)*65 + k], a0);
            a1 = fmaf(tv, lds[L_WTR + (1*JPB + jj)*65 + k], a1);
            a2 = fmaf(tv, lds[L_WTR + (2*JPB + jj)*65 + k], a2);
            a3 = fmaf(tv, lds[L_WTR + (3*JPB + jj)*65 + k], a3);
            a4 = fmaf(tv, lds[L_WTR + (4*JPB + jj)*65 + k], a4);
          }
          float rc = sigf(a1)*s2c + sigf(a2)*s1c + sigf(a0)*tanhf(a4);
          float rh = sigf(a3)*tanhf(rc);
          s2base[j] = rh;
          s2base[HD + j] = rc;
        } else {
          int b = shl[rr - nred];
          int sp = sptr[b], bp = bptr[b];
          const float* src = bufs + ((size_t)((b0+b)*SQ + bp))*DW;
          float* dst = stack + ((size_t)((b0+b)*SQ + sp))*DW;
          dst[j] = src[j];
          dst[HD + j] = src[HD + j];
        }
      }
    } else if (role == NE) {   // logits
      if (tid < 32) {
        int b = tid >> 1, c = tid & 1;
        const float* th = thbuf + ((size_t)(t & 1)*HB + (b0 + b))*TK;
        float s = btrans[c];
        #pragma unroll 8
        for (int u = 0; u < TK; ++u) s = fmaf(th[u], Wtrans[u*2 + c], s);
        out[(size_t)(b0 + b)*OUTW + HD + 2*t + c] = s;
      }
    }

    __syncthreads();
    if (tid < 16) {
      if (!((w >> tid) & 1)) { sptr[tid] += 1; bptr[tid] += 1; }
      else                   { sptr[tid] -= 1; }
    }

    ++epoch;
    xbar(role, epoch, slots, flag, broken);   // stack(t) visible
  }

  // ---- final sentence encoding ----
  if (isE && tid < 192) {
    int b = tid / JPB, jj = tid % JPB;
    int j = e*JPB + jj;
    int sp = sptr[b] - 1; if (sp < 0) sp = 0;
    out[(size_t)(b0 + b)*OUTW + j] =
        stack[((size_t)((b0 + b)*SQ + sp))*DW + j];
  }
}

// ---------------------------------------------------------------------
extern "C" void kernel_launch(void* const* d_in, const int* in_sizes, int n_in,
                              void* d_out, int out_size, void* d_ws, size_t ws_size,
                              hipStream_t stream) {
  const float* bufs   = (const float*)d_in[0];
  const int*   trans  = (const int*)  d_in[1];
  const float* Wbuf   = (const float*)d_in[2];
  const float* Ws1    = (const float*)d_in[3];
  const float* Ws2    = (const float*)d_in[4];
  const float* Wih    = (const float*)d_in[5];
  const float* Whh    = (const float*)d_in[6];
  const float* Wtrans = (const float*)d_in[7];
  const float* btrans = (const float*)d_in[8];
  const float* Wl     = (const float*)d_in[9];
  const float* Wr     = (const float*)d_in[10];
  const float* Wtrk   = (const float*)d_in[11];
  const float* bredv  = (const float*)d_in[12];
  float* ws  = (float*)d_ws;
  float* out = (float*)d_out;

  if (ws_size < (size_t)WS_FLOATS * sizeof(float)) return;

  {
    int total = N_WCT + N_TH + N_BAR + 8*NSTEP;
    prep_a<<<(total + 255) / 256, 256, 0, stream>>>(Wbuf, Ws1, Ws2, trans, ws);
  }
  {
    int total = N_WEB + N_WTB + N_WTR;
    prep_b<<<(total + 255) / 256, 256, 0, stream>>>(Wih, Whh, Wl, Wr, Wtrk, ws);
  }
  (void)hipFuncSetAttribute((const void*)spinn_kernel,
                            hipFuncAttributeMaxDynamicSharedMemorySize, 160000);
  spinn_kernel<<<256, 256, LDS_FLOATS * sizeof(float), stream>>>(
      bufs, Wtrans, btrans, bredv, ws, out);
}